// Round 5
// baseline (342.745 us; speedup 1.0000x reference)
//
#include <hip/hip_runtime.h>
#include <hip/hip_bf16.h>
#include <cstdint>
#include <cstddef>

#define B_ 4
#define L_ 4096
#define D_ 1024
#define FF_ 2048
#define ROWS (B_ * L_)   // 16384
#define EPS_ 1e-5f
#define CG 64            // conv chunks
#define CC 64            // conv chunk length (L_/CG)

typedef __attribute__((ext_vector_type(8))) __bf16 bf16x8;
typedef __attribute__((ext_vector_type(4))) float f32x4;
typedef __attribute__((ext_vector_type(16))) float f32x16;
typedef __attribute__((ext_vector_type(4))) unsigned short us4;

__device__ __forceinline__ float bf2f(unsigned short u) {
  union { unsigned int i; float f; } v; v.i = ((unsigned int)u) << 16; return v.f;
}
__device__ __forceinline__ unsigned short f2bf(float f) {
  union { float f; unsigned int i; } v; v.f = f;
  unsigned int r = v.i + 0x7fffu + ((v.i >> 16) & 1u);
  return (unsigned short)(r >> 16);
}

// ---------------- weight transpose + cast: in [K,N] f32 -> out [N,K] bf16 ----
__global__ __launch_bounds__(256) void transpose_cast(
    const float* __restrict__ in, unsigned short* __restrict__ out, int K, int N) {
  __shared__ float tb[32][33];
  int n0 = blockIdx.x * 32, k0 = blockIdx.y * 32;
  int tx = threadIdx.x & 31, ty = threadIdx.x >> 5;  // 32 x 8
#pragma unroll
  for (int i = 0; i < 4; ++i) {
    int k = ty + i * 8;
    tb[k][tx] = in[(size_t)(k0 + k) * N + n0 + tx];
  }
  __syncthreads();
#pragma unroll
  for (int i = 0; i < 4; ++i) {
    int n = ty + i * 8;
    out[(size_t)(n0 + n) * K + k0 + tx] = f2bf(tb[tx][n]);
  }
}

// ---------------- LN1: x -> xn bf16 (LayerNorm), xb bf16 (plain cast) --------
__global__ __launch_bounds__(256) void ln1_kernel(
    const float* __restrict__ x, const float* __restrict__ g, const float* __restrict__ b,
    unsigned short* __restrict__ xn, unsigned short* __restrict__ xb) {
  int row = blockIdx.x;
  int t = threadIdx.x;
  const float4* xr = (const float4*)(x + (size_t)row * D_);
  float4 v = xr[t];
  float s = v.x + v.y + v.z + v.w;
  float sq = v.x * v.x + v.y * v.y + v.z * v.z + v.w * v.w;
#pragma unroll
  for (int off = 32; off > 0; off >>= 1) {
    s += __shfl_down(s, off);
    sq += __shfl_down(sq, off);
  }
  __shared__ float ls[4], lq[4];
  int lane = t & 63, w = t >> 6;
  if (lane == 0) { ls[w] = s; lq[w] = sq; }
  __syncthreads();
  s = ls[0] + ls[1] + ls[2] + ls[3];
  sq = lq[0] + lq[1] + lq[2] + lq[3];
  float mean = s * (1.0f / D_);
  float var = sq * (1.0f / D_) - mean * mean;
  float rstd = rsqrtf(var + EPS_);
  float4 gv = ((const float4*)g)[t];
  float4 bv = ((const float4*)b)[t];
  us4 o, ob;
  o.x = f2bf((v.x - mean) * rstd * gv.x + bv.x);
  o.y = f2bf((v.y - mean) * rstd * gv.y + bv.y);
  o.z = f2bf((v.z - mean) * rstd * gv.z + bv.z);
  o.w = f2bf((v.w - mean) * rstd * gv.w + bv.w);
  ob.x = f2bf(v.x); ob.y = f2bf(v.y); ob.z = f2bf(v.z); ob.w = f2bf(v.w);
  ((us4*)(xn + (size_t)row * D_))[t] = o;
  ((us4*)(xb + (size_t)row * D_))[t] = ob;
}

// ---------------- conv pass 1: per-chunk local recurrence --------------------
__global__ __launch_bounds__(256) void conv_pass1(
    const unsigned short* __restrict__ xn, const float* __restrict__ ph_re,
    const float* __restrict__ ph_im, float2* __restrict__ rloc) {
  int d = blockIdx.x * 256 + threadIdx.x;
  int g = blockIdx.y, b = blockIdx.z;
  float re = ph_re[d], im = ph_im[d];
  float a = sqrtf(re * re + im * im);
  float sc = expf(-a) / a;
  float pr = re * sc, pi = im * sc;
  float rr = 0.f, ri = 0.f;
  const unsigned short* xp = xn + ((size_t)(b * L_ + g * CC)) * D_ + d;
#pragma unroll 8
  for (int l = 0; l < CC; ++l) {
    float xv = bf2f(xp[(size_t)l * D_]);
    float nr = pr * rr - pi * ri + xv;
    ri = pr * ri + pi * rr;
    rr = nr;
  }
  rloc[((size_t)(b * CG + g)) * D_ + d] = make_float2(rr, ri);
}

// ---------------- conv pass 2: scan over chunks (batch-8 prefetched) ---------
__global__ __launch_bounds__(256) void conv_pass2(
    const float* __restrict__ ph_re, const float* __restrict__ ph_im,
    const float2* __restrict__ rloc, float2* __restrict__ carry) {
  int idx = blockIdx.x * 256 + threadIdx.x;  // 0..B*D-1
  int b = idx >> 10, d = idx & (D_ - 1);
  float re = ph_re[d], im = ph_im[d];
  float a = sqrtf(re * re + im * im);
  float th = atan2f(im, re);
  float rho = expf(-a * (float)CC);
  float ang = th * (float)CC;
  float pcr = rho * cosf(ang), pci = rho * sinf(ang);
  float cr = 0.f, ci = 0.f;
  for (int g0 = 0; g0 < CG; g0 += 8) {
    float2 rl[8];
    float2 cw[8];
#pragma unroll
    for (int i = 0; i < 8; ++i)
      rl[i] = rloc[((size_t)(b * CG + g0 + i)) * D_ + d];
#pragma unroll
    for (int i = 0; i < 8; ++i) {
      cw[i] = make_float2(cr, ci);
      float nr = pcr * cr - pci * ci + rl[i].x;
      ci = pcr * ci + pci * cr + rl[i].y;
      cr = nr;
    }
#pragma unroll
    for (int i = 0; i < 8; ++i)
      carry[((size_t)(b * CG + g0 + i)) * D_ + d] = cw[i];
  }
}

// ---------------- conv pass 3: outputs -------------------------------------
__global__ __launch_bounds__(256) void conv_pass3(
    const unsigned short* __restrict__ xn,
    const float* __restrict__ ph_re, const float* __restrict__ ph_im,
    const float* __restrict__ phi_re, const float* __restrict__ phi_im,
    const float* __restrict__ lci_re, const float* __restrict__ lci_im,
    const float2* __restrict__ carry, unsigned short* __restrict__ cout) {
  int d = blockIdx.x * 256 + threadIdx.x;
  int g = blockIdx.y, b = blockIdx.z;
  float re = ph_re[d], im = ph_im[d];
  float a = sqrtf(re * re + im * im);
  float sc = expf(-a) / a;
  float pr = re * sc, pi = im * sc;
  float th = atan2f(im, re);
  int l0 = g * CC;
  float rho = expf(-a * (float)(l0 + 1));
  float ang = th * (float)(l0 + 1);
  float prr = rho * cosf(ang), pri = rho * sinf(ang);
  float fr = phi_re[d], fi = phi_im[d];
  float qr = lci_re[d], qi = lci_im[d];
  float2 cv = carry[((size_t)(b * CG + g)) * D_ + d];
  float rr = cv.x, ri = cv.y;
  const unsigned short* xp = xn + ((size_t)(b * L_ + l0)) * D_ + d;
  unsigned short* cp = cout + ((size_t)(b * L_ + l0)) * D_ + d;
#pragma unroll 4
  for (int l = 0; l < CC; ++l) {
    float xv = bf2f(xp[(size_t)l * D_]);
    float nr = pr * rr - pi * ri + xv;
    ri = pr * ri + pi * rr;
    rr = nr;
    float outv = fr * rr - fi * ri + qr * prr - qi * pri;  // Re(phi*r + lci*p)
    cp[(size_t)l * D_] = f2bf(outv);
    float pn = pr * prr - pi * pri;
    pri = pr * pri + pi * prr;
    prr = pn;
  }
}

// ---------------- LN2b: x3 = LN(x2) bf16 (x2 already in d_out) --------------
__global__ __launch_bounds__(256) void ln2b_kernel(
    const float* __restrict__ x2, const float* __restrict__ g, const float* __restrict__ b,
    unsigned short* __restrict__ x3) {
  int row = blockIdx.x;
  int t = threadIdx.x;
  size_t base = (size_t)row * D_;
  float4 v = ((const float4*)(x2 + base))[t];
  float s = v.x + v.y + v.z + v.w;
  float sq = v.x * v.x + v.y * v.y + v.z * v.z + v.w * v.w;
#pragma unroll
  for (int off = 32; off > 0; off >>= 1) {
    s += __shfl_down(s, off);
    sq += __shfl_down(sq, off);
  }
  __shared__ float ls[4], lq[4];
  int lane = t & 63, w = t >> 6;
  if (lane == 0) { ls[w] = s; lq[w] = sq; }
  __syncthreads();
  s = ls[0] + ls[1] + ls[2] + ls[3];
  sq = lq[0] + lq[1] + lq[2] + lq[3];
  float mean = s * (1.0f / D_);
  float var = sq * (1.0f / D_) - mean * mean;
  float rstd = rsqrtf(var + EPS_);
  float4 gv = ((const float4*)g)[t];
  float4 bv = ((const float4*)b)[t];
  us4 o;
  o.x = f2bf((v.x - mean) * rstd * gv.x + bv.x);
  o.y = f2bf((v.y - mean) * rstd * gv.y + bv.y);
  o.z = f2bf((v.z - mean) * rstd * gv.z + bv.z);
  o.w = f2bf((v.w - mean) * rstd * gv.w + bv.w);
  ((us4*)(x3 + base))[t] = o;
}

// ============================================================================
// GEMM: A[M,K] bf16 @ Bt[N,K] bf16 -> C [M,N], 32x32x16 MFMA.
// BM=256, BN=256, BK=64. 512 threads = 8 waves (2M x 4N), per-wave 128x64 =
// acc[4][2] of f32x16. LDS: A dbuf (2x32K) + B ring (3x32K) = 160 KiB.
// ONE sync point per K-tile: {stage A(t+1),B(t+2); 24 ds_read + 32 MFMA
// (compiler-interleaved, auto counted lgkmcnt); vmcnt(4); s_barrier}.
// Queue at wait: [B(t+1), A(t+1), B(t+2)] -> vmcnt(4) lands tile t+1 exactly.
// XOR-swizzled LDS (16B chunk ^= row&7), pre-swizzled global source:
// quarter-wave reads 16 consecutive rows at one chunk -> <=2-way (free).
// ============================================================================
__device__ __forceinline__ void gld_lds16(const unsigned short* gp, unsigned short* lp) {
  __builtin_amdgcn_global_load_lds(
      (const __attribute__((address_space(1))) unsigned int*)gp,
      (__attribute__((address_space(3))) unsigned int*)lp, 16, 0, 0);
}

template <int SILU, int RES, int OUT_BF16, int GATE>
__global__ __launch_bounds__(512, 2) void gemm_bt(
    const unsigned short* __restrict__ A, const unsigned short* __restrict__ Bt,
    const float* __restrict__ bias, const float* __restrict__ res,
    const unsigned short* __restrict__ gate, const float* __restrict__ xres,
    void* __restrict__ Cv, int NB, int GROUP, int N, int K) {
  __shared__ unsigned short As[2][256 * 64];  // 2 x 32 KiB
  __shared__ unsigned short Bs[3][256 * 64];  // 3 x 32 KiB

  int nwg = gridDim.x;
  int xcd = blockIdx.x & 7;
  int lo = blockIdx.x >> 3;
  int q = nwg >> 3;               // blocks per XCD
  int gsz = GROUP * NB;
  int g_ = lo / gsz, r_ = lo % gsz;
  int n_ = r_ / GROUP, ml = r_ - n_ * GROUP;
  int Mx = q / NB;                // m-rows per XCD
  int bm0 = (xcd * Mx + g_ * GROUP + ml) * 256;
  int bn0 = n_ * 256;

  int t = threadIdx.x;
  int lane = t & 63, w = t >> 6;
  int wr = w >> 2, wc = w & 3;          // 2M x 4N waves
  int r32 = lane & 31, half = lane >> 5;
  int sx = r32 & 7;                     // swizzle key (row&7 of all frag rows)
  int rA0 = wr * 128 + r32;             // + mi*32
  int rB0 = wc * 64 + r32;              // + ni*32

  int nt = K >> 6;

  // staging source (pre-swizzled): thread t covers row tr of each 64-row chunk
  int tr = t >> 3;
  int jx = (t & 7) ^ (tr & 7);
  const unsigned short* pA = A + (size_t)(bm0 + tr) * K + jx * 8;
  const unsigned short* pB = Bt + (size_t)(bn0 + tr) * K + jx * 8;

  auto stageA = [&](int kt2, int slot) {
#pragma unroll
    for (int c = 0; c < 4; ++c)
      gld_lds16(pA + (size_t)kt2 * 64 + (size_t)c * 64 * K, &As[slot][c * 4096 + t * 8]);
  };
  auto stageB = [&](int kt2, int slot) {
#pragma unroll
    for (int c = 0; c < 4; ++c)
      gld_lds16(pB + (size_t)kt2 * 64 + (size_t)c * 64 * K, &Bs[slot][c * 4096 + t * 8]);
  };

  f32x16 acc[4][2] = {};

  // prologue: A0, B0, B1 (12 loads, order matters); wait A0+B0 (B1 in flight)
  stageA(0, 0);
  stageB(0, 0);
  stageB(1, 1);
  asm volatile("s_waitcnt vmcnt(4)" ::: "memory");
  __builtin_amdgcn_s_barrier();

  int sa = 0, sb = 0;
  for (int kt = 0; kt < nt; ++kt) {
    const unsigned short* as = As[sa];
    const unsigned short* bs = Bs[sb];
    int sbn = sb + 2; if (sbn >= 3) sbn -= 3;
    bool pfA = kt + 1 < nt;
    bool pfB = kt + 2 < nt;
    if (pfA) stageA(kt + 1, sa ^ 1);   // issue order: A(t+1) then B(t+2)
    if (pfB) stageB(kt + 2, sbn);

    // compute tile kt: 4 k-steps of 16, compiler interleaves ds_read/MFMA
#pragma unroll
    for (int ks = 0; ks < 4; ++ks) {
      int ko = (((half + 2 * ks) ^ sx)) * 8;  // swizzled 16B chunk offset (shorts)
      bf16x8 a[4], bfr[2];
#pragma unroll
      for (int mi = 0; mi < 4; ++mi)
        a[mi] = *(const bf16x8*)&as[(rA0 + mi * 32) * 64 + ko];
#pragma unroll
      for (int ni = 0; ni < 2; ++ni)
        bfr[ni] = *(const bf16x8*)&bs[(rB0 + ni * 32) * 64 + ko];
#pragma unroll
      for (int mi = 0; mi < 4; ++mi)
#pragma unroll
        for (int ni = 0; ni < 2; ++ni)
          acc[mi][ni] = __builtin_amdgcn_mfma_f32_32x32x16_bf16(a[mi], bfr[ni], acc[mi][ni], 0, 0, 0);
    }

    if (pfB) {
      asm volatile("s_waitcnt vmcnt(4)" ::: "memory");  // tile kt+1 fully landed
    } else if (pfA) {
      asm volatile("s_waitcnt vmcnt(0)" ::: "memory");  // tail drain
    }
    if (pfA) __builtin_amdgcn_s_barrier();
    sa ^= 1;
    sb += 1; if (sb == 3) sb = 0;
  }

  // epilogue: D layout (32x32): col=lane&31, row=(reg&3)+8*(reg>>2)+4*(lane>>5)
#pragma unroll
  for (int mi = 0; mi < 4; ++mi) {
#pragma unroll
    for (int ni = 0; ni < 2; ++ni) {
#pragma unroll
      for (int rg = 0; rg < 16; ++rg) {
        int row = bm0 + wr * 128 + mi * 32 + (rg & 3) + 8 * (rg >> 2) + 4 * half;
        int col = bn0 + wc * 64 + ni * 32 + r32;
        size_t o = (size_t)row * N + col;
        float v = acc[mi][ni][rg] + bias[col];
        if (SILU) v = v / (1.0f + __expf(-v));
        if (GATE) v = bf2f(gate[o]) * v + xres[o];
        if (RES) v += res[o];
        if (OUT_BF16)
          ((unsigned short*)Cv)[o] = f2bf(v);
        else
          ((float*)Cv)[o] = v;
      }
    }
  }
}

// ---------------------------------------------------------------------------
extern "C" void kernel_launch(void* const* d_in, const int* in_sizes, int n_in,
                              void* d_out, int out_size, void* d_ws, size_t ws_size,
                              hipStream_t stream) {
  const float* x      = (const float*)d_in[0];
  const float* ln_g   = (const float*)d_in[1];
  const float* ln_b   = (const float*)d_in[2];
  const float* fc_w   = (const float*)d_in[3];
  const float* fc_b   = (const float*)d_in[4];
  const float* w1     = (const float*)d_in[5];
  const float* b1     = (const float*)d_in[6];
  const float* w2     = (const float*)d_in[7];
  const float* b2     = (const float*)d_in[8];
  const float* ph_re  = (const float*)d_in[9];
  const float* ph_im  = (const float*)d_in[10];
  const float* phi_re = (const float*)d_in[11];
  const float* phi_im = (const float*)d_in[12];
  const float* lci_re = (const float*)d_in[13];
  const float* lci_im = (const float*)d_in[14];
  float* out = (float*)d_out;

  char* ws = (char*)d_ws;
  const size_t SZ_BF = (size_t)ROWS * D_ * 2;  // 33,554,432 bytes
  unsigned short* xn    = (unsigned short*)(ws);               // LN1 out (conv input)
  unsigned short* cbuf  = (unsigned short*)(ws + SZ_BF);       // conv output
  unsigned short* xb_x3 = (unsigned short*)(ws + 2 * SZ_BF);   // x bf16, then x3 (after gemm1)
  unsigned short* h1    = (unsigned short*)(ws + 3 * SZ_BF);   // [ROWS, FF] bf16 (2*SZ_BF)
  unsigned short* fc_wt = (unsigned short*)(ws + 5 * SZ_BF);
  unsigned short* w1t   = (unsigned short*)(ws + 5 * SZ_BF + (size_t)D_ * D_ * 2);
  unsigned short* w2t   = (unsigned short*)(ws + 5 * SZ_BF + (size_t)D_ * D_ * 2 + (size_t)D_ * FF_ * 2);
  float2* rloc  = (float2*)(ws + 5 * SZ_BF + (size_t)D_ * D_ * 2 + 2 * (size_t)D_ * FF_ * 2);
  float2* carry = rloc + (size_t)B_ * CG * D_;

  // weight prep (bf16, transposed to [N,K])
  transpose_cast<<<dim3(D_ / 32, D_ / 32), 256, 0, stream>>>(fc_w, fc_wt, D_, D_);
  transpose_cast<<<dim3(FF_ / 32, D_ / 32), 256, 0, stream>>>(w1, w1t, D_, FF_);
  transpose_cast<<<dim3(D_ / 32, FF_ / 32), 256, 0, stream>>>(w2, w2t, FF_, D_);

  // LN1 + cast
  ln1_kernel<<<ROWS, 256, 0, stream>>>(x, ln_g, ln_b, xn, xb_x3);

  // conv (chunked scan)
  conv_pass1<<<dim3(D_ / 256, CG, B_), 256, 0, stream>>>(xn, ph_re, ph_im, rloc);
  conv_pass2<<<dim3((B_ * D_) / 256), 256, 0, stream>>>(ph_re, ph_im, rloc, carry);
  conv_pass3<<<dim3(D_ / 256, CG, B_), 256, 0, stream>>>(xn, ph_re, ph_im, phi_re, phi_im,
                                                         lci_re, lci_im, carry, cbuf);

  // x2 = c * silu(x @ fc_w + fc_b) + x  (fused gate, f32 -> d_out)
  gemm_bt<1, 0, 0, 1><<<(ROWS / 256) * (D_ / 256), 512, 0, stream>>>(
      xb_x3, fc_wt, fc_b, nullptr, cbuf, x, out, D_ / 256, 4, D_, D_);

  // x3 = LN(x2) (bf16, reuses xb region)
  ln2b_kernel<<<ROWS, 256, 0, stream>>>(out, ln_g, ln_b, xb_x3);

  // h1 = silu(x3 @ w1 + b1)
  gemm_bt<1, 0, 1, 0><<<(ROWS / 256) * (FF_ / 256), 512, 0, stream>>>(
      xb_x3, w1t, b1, nullptr, nullptr, nullptr, h1, FF_ / 256, 4, FF_, D_);

  // out = x2 + h1 @ w2 + b2   (in-place residual from d_out)
  gemm_bt<0, 1, 0, 0><<<(ROWS / 256) * (D_ / 256), 512, 0, stream>>>(
      h1, w2t, b2, out, nullptr, nullptr, out, D_ / 256, 2, D_, FF_);
}

// Round 6
// 320.374 us; speedup vs baseline: 1.0698x; 1.0698x over previous
//
#include <hip/hip_runtime.h>
#include <hip/hip_bf16.h>
#include <cstdint>
#include <cstddef>

#define B_ 4
#define L_ 4096
#define D_ 1024
#define FF_ 2048
#define ROWS (B_ * L_)   // 16384
#define EPS_ 1e-5f
#define CG 64            // conv chunks
#define CC 64            // conv chunk length (L_/CG)

typedef __attribute__((ext_vector_type(8))) __bf16 bf16x8;
typedef __attribute__((ext_vector_type(4))) float f32x4;
typedef __attribute__((ext_vector_type(4))) unsigned short us4;

__device__ __forceinline__ float bf2f(unsigned short u) {
  union { unsigned int i; float f; } v; v.i = ((unsigned int)u) << 16; return v.f;
}
__device__ __forceinline__ unsigned short f2bf(float f) {
  union { float f; unsigned int i; } v; v.f = f;
  unsigned int r = v.i + 0x7fffu + ((v.i >> 16) & 1u);
  return (unsigned short)(r >> 16);
}

// ---------------- weight transpose + cast: in [K,N] f32 -> out [N,K] bf16 ----
__global__ __launch_bounds__(256) void transpose_cast(
    const float* __restrict__ in, unsigned short* __restrict__ out, int K, int N) {
  __shared__ float tb[32][33];
  int n0 = blockIdx.x * 32, k0 = blockIdx.y * 32;
  int tx = threadIdx.x & 31, ty = threadIdx.x >> 5;  // 32 x 8
#pragma unroll
  for (int i = 0; i < 4; ++i) {
    int k = ty + i * 8;
    tb[k][tx] = in[(size_t)(k0 + k) * N + n0 + tx];
  }
  __syncthreads();
#pragma unroll
  for (int i = 0; i < 4; ++i) {
    int n = ty + i * 8;
    out[(size_t)(n0 + n) * K + k0 + tx] = f2bf(tb[tx][n]);
  }
}

// ---------------- LN1: x -> xn bf16 (LayerNorm), xb bf16 (plain cast) --------
__global__ __launch_bounds__(256) void ln1_kernel(
    const float* __restrict__ x, const float* __restrict__ g, const float* __restrict__ b,
    unsigned short* __restrict__ xn, unsigned short* __restrict__ xb) {
  int row = blockIdx.x;
  int t = threadIdx.x;
  const float4* xr = (const float4*)(x + (size_t)row * D_);
  float4 v = xr[t];
  float s = v.x + v.y + v.z + v.w;
  float sq = v.x * v.x + v.y * v.y + v.z * v.z + v.w * v.w;
#pragma unroll
  for (int off = 32; off > 0; off >>= 1) {
    s += __shfl_down(s, off);
    sq += __shfl_down(sq, off);
  }
  __shared__ float ls[4], lq[4];
  int lane = t & 63, w = t >> 6;
  if (lane == 0) { ls[w] = s; lq[w] = sq; }
  __syncthreads();
  s = ls[0] + ls[1] + ls[2] + ls[3];
  sq = lq[0] + lq[1] + lq[2] + lq[3];
  float mean = s * (1.0f / D_);
  float var = sq * (1.0f / D_) - mean * mean;
  float rstd = rsqrtf(var + EPS_);
  float4 gv = ((const float4*)g)[t];
  float4 bv = ((const float4*)b)[t];
  us4 o, ob;
  o.x = f2bf((v.x - mean) * rstd * gv.x + bv.x);
  o.y = f2bf((v.y - mean) * rstd * gv.y + bv.y);
  o.z = f2bf((v.z - mean) * rstd * gv.z + bv.z);
  o.w = f2bf((v.w - mean) * rstd * gv.w + bv.w);
  ob.x = f2bf(v.x); ob.y = f2bf(v.y); ob.z = f2bf(v.z); ob.w = f2bf(v.w);
  ((us4*)(xn + (size_t)row * D_))[t] = o;
  ((us4*)(xb + (size_t)row * D_))[t] = ob;
}

// ---------------- conv pass 1: per-chunk local recurrence --------------------
__global__ __launch_bounds__(256) void conv_pass1(
    const unsigned short* __restrict__ xn, const float* __restrict__ ph_re,
    const float* __restrict__ ph_im, float2* __restrict__ rloc) {
  int d = blockIdx.x * 256 + threadIdx.x;
  int g = blockIdx.y, b = blockIdx.z;
  float re = ph_re[d], im = ph_im[d];
  float a = sqrtf(re * re + im * im);
  float sc = expf(-a) / a;
  float pr = re * sc, pi = im * sc;
  float rr = 0.f, ri = 0.f;
  const unsigned short* xp = xn + ((size_t)(b * L_ + g * CC)) * D_ + d;
#pragma unroll 8
  for (int l = 0; l < CC; ++l) {
    float xv = bf2f(xp[(size_t)l * D_]);
    float nr = pr * rr - pi * ri + xv;
    ri = pr * ri + pi * rr;
    rr = nr;
  }
  rloc[((size_t)(b * CG + g)) * D_ + d] = make_float2(rr, ri);
}

// ---------------- conv pass 2: scan over chunks (batch-8 prefetched) ---------
__global__ __launch_bounds__(256) void conv_pass2(
    const float* __restrict__ ph_re, const float* __restrict__ ph_im,
    const float2* __restrict__ rloc, float2* __restrict__ carry) {
  int idx = blockIdx.x * 256 + threadIdx.x;  // 0..B*D-1
  int b = idx >> 10, d = idx & (D_ - 1);
  float re = ph_re[d], im = ph_im[d];
  float a = sqrtf(re * re + im * im);
  float th = atan2f(im, re);
  float rho = expf(-a * (float)CC);
  float ang = th * (float)CC;
  float pcr = rho * cosf(ang), pci = rho * sinf(ang);
  float cr = 0.f, ci = 0.f;
  for (int g0 = 0; g0 < CG; g0 += 8) {
    float2 rl[8];
    float2 cw[8];
#pragma unroll
    for (int i = 0; i < 8; ++i)
      rl[i] = rloc[((size_t)(b * CG + g0 + i)) * D_ + d];
#pragma unroll
    for (int i = 0; i < 8; ++i) {
      cw[i] = make_float2(cr, ci);
      float nr = pcr * cr - pci * ci + rl[i].x;
      ci = pcr * ci + pci * cr + rl[i].y;
      cr = nr;
    }
#pragma unroll
    for (int i = 0; i < 8; ++i)
      carry[((size_t)(b * CG + g0 + i)) * D_ + d] = cw[i];
  }
}

// ---------------- conv pass 3: outputs -------------------------------------
__global__ __launch_bounds__(256) void conv_pass3(
    const unsigned short* __restrict__ xn,
    const float* __restrict__ ph_re, const float* __restrict__ ph_im,
    const float* __restrict__ phi_re, const float* __restrict__ phi_im,
    const float* __restrict__ lci_re, const float* __restrict__ lci_im,
    const float2* __restrict__ carry, unsigned short* __restrict__ cout) {
  int d = blockIdx.x * 256 + threadIdx.x;
  int g = blockIdx.y, b = blockIdx.z;
  float re = ph_re[d], im = ph_im[d];
  float a = sqrtf(re * re + im * im);
  float sc = expf(-a) / a;
  float pr = re * sc, pi = im * sc;
  float th = atan2f(im, re);
  int l0 = g * CC;
  float rho = expf(-a * (float)(l0 + 1));
  float ang = th * (float)(l0 + 1);
  float prr = rho * cosf(ang), pri = rho * sinf(ang);
  float fr = phi_re[d], fi = phi_im[d];
  float qr = lci_re[d], qi = lci_im[d];
  float2 cv = carry[((size_t)(b * CG + g)) * D_ + d];
  float rr = cv.x, ri = cv.y;
  const unsigned short* xp = xn + ((size_t)(b * L_ + l0)) * D_ + d;
  unsigned short* cp = cout + ((size_t)(b * L_ + l0)) * D_ + d;
#pragma unroll 4
  for (int l = 0; l < CC; ++l) {
    float xv = bf2f(xp[(size_t)l * D_]);
    float nr = pr * rr - pi * ri + xv;
    ri = pr * ri + pi * rr;
    rr = nr;
    float outv = fr * rr - fi * ri + qr * prr - qi * pri;  // Re(phi*r + lci*p)
    cp[(size_t)l * D_] = f2bf(outv);
    float pn = pr * prr - pi * pri;
    pri = pr * pri + pi * prr;
    prr = pn;
  }
}

// ---------------- LN2b: x3 = LN(x2) bf16 (x2 already in d_out) --------------
__global__ __launch_bounds__(256) void ln2b_kernel(
    const float* __restrict__ x2, const float* __restrict__ g, const float* __restrict__ b,
    unsigned short* __restrict__ x3) {
  int row = blockIdx.x;
  int t = threadIdx.x;
  size_t base = (size_t)row * D_;
  float4 v = ((const float4*)(x2 + base))[t];
  float s = v.x + v.y + v.z + v.w;
  float sq = v.x * v.x + v.y * v.y + v.z * v.z + v.w * v.w;
#pragma unroll
  for (int off = 32; off > 0; off >>= 1) {
    s += __shfl_down(s, off);
    sq += __shfl_down(sq, off);
  }
  __shared__ float ls[4], lq[4];
  int lane = t & 63, w = t >> 6;
  if (lane == 0) { ls[w] = s; lq[w] = sq; }
  __syncthreads();
  s = ls[0] + ls[1] + ls[2] + ls[3];
  sq = lq[0] + lq[1] + lq[2] + lq[3];
  float mean = s * (1.0f / D_);
  float var = sq * (1.0f / D_) - mean * mean;
  float rstd = rsqrtf(var + EPS_);
  float4 gv = ((const float4*)g)[t];
  float4 bv = ((const float4*)b)[t];
  us4 o;
  o.x = f2bf((v.x - mean) * rstd * gv.x + bv.x);
  o.y = f2bf((v.y - mean) * rstd * gv.y + bv.y);
  o.z = f2bf((v.z - mean) * rstd * gv.z + bv.z);
  o.w = f2bf((v.w - mean) * rstd * gv.w + bv.w);
  ((us4*)(x3 + base))[t] = o;
}

// ============================================================================
// GEMM: A[M,K] bf16 @ Bt[N,K] bf16 -> C [M,N], m201-template port.
// BM=BN=256, BK=64, 16x16x32 MFMA. 512 thr = 8 waves (2M x 4N), wave out 128x64.
// LDS: full dbuf 2 x (A 32K + B 32K) = 128 KiB. 4 gray-code quadrant phases
// per K-tile: q1(mh0,nh0) reads a0+b0; q2(mh0,nh1) reads b1; q3(mh1,nh1)
// reads a1; q4(mh1,nh0) reuses a1,b0. 24 ds_read_b128/tile/wave (minimum).
// Chunk-granular staging (1 chunk = 64 rows = 1 gld_lds/thread), 2/phase:
//   q1: B(T+1)c0,c1   q2: B(T+1)c2,c3 + vmcnt(5)
//   q3: A(T+1)c1, A(T+2)c0   q4: A(T+1)c3, A(T+2)c2 + vmcnt(4)
// Ledger-derived counted waits (never 0 mid-loop); tail clamps exact.
// XOR-swizzled LDS (16B chunk ^= row&7), pre-swizzled global source
// (proven 0-conflict pattern from R3/R4).
// ============================================================================
__device__ __forceinline__ void gld_lds16(const unsigned short* gp, unsigned short* lp) {
  __builtin_amdgcn_global_load_lds(
      (const __attribute__((address_space(1))) unsigned int*)gp,
      (__attribute__((address_space(3))) unsigned int*)lp, 16, 0, 0);
}

#define PHASE_SYNC()                                         \
  __builtin_amdgcn_s_barrier();                              \
  asm volatile("s_waitcnt lgkmcnt(0)" ::: "memory");         \
  __builtin_amdgcn_sched_barrier(0);                         \
  __builtin_amdgcn_s_setprio(1);

#define PHASE_END()                                          \
  __builtin_amdgcn_s_setprio(0);                             \
  __builtin_amdgcn_s_barrier();

template <int SILU, int RES, int OUT_BF16, int GATE>
__global__ __launch_bounds__(512, 2) void gemm_bt(
    const unsigned short* __restrict__ A, const unsigned short* __restrict__ Bt,
    const float* __restrict__ bias, const float* __restrict__ res,
    const unsigned short* __restrict__ gate, const float* __restrict__ xres,
    void* __restrict__ Cv, int NB, int GROUP, int N, int K) {
  __shared__ unsigned short As[2][256 * 64];  // 2 x 32 KiB
  __shared__ unsigned short Bs[2][256 * 64];  // 2 x 32 KiB

  int nwg = gridDim.x;
  int xcd = blockIdx.x & 7;
  int lo = blockIdx.x >> 3;
  int q = nwg >> 3;               // blocks per XCD
  int gsz = GROUP * NB;
  int g_ = lo / gsz, r_ = lo % gsz;
  int n_ = r_ / GROUP, ml = r_ - n_ * GROUP;
  int Mx = q / NB;                // m-rows per XCD
  int bm0 = (xcd * Mx + g_ * GROUP + ml) * 256;
  int bn0 = n_ * 256;

  int t = threadIdx.x;
  int lane = t & 63, w = t >> 6;
  int wr = w >> 2, wc = w & 3;          // 2M x 4N waves
  int frr = lane & 15, cl = lane >> 4;  // fragment row, chunk-group (0..3)
  int fx = frr & 7;
  int rA0 = wr * 128 + frr;
  int rB0 = wc * 64 + frr;
  int ko0 = (cl ^ fx) * 8;              // ks=0 swizzled 16B chunk
  int ko1 = ((4 + cl) ^ fx) * 8;        // ks=1

  int nt = K >> 6;

  // staging source (pre-swizzled): thread t covers row tr of each 64-row chunk
  int tr = t >> 3;
  int jx = (t & 7) ^ (tr & 7);
  const unsigned short* pA = A + (size_t)(bm0 + tr) * K + jx * 8;
  const unsigned short* pB = Bt + (size_t)(bn0 + tr) * K + jx * 8;

  auto stA = [&](int kt2, int c) {  // chunk c (64 rows) of tile kt2
    gld_lds16(pA + (size_t)kt2 * 64 + (size_t)c * 64 * K, &As[kt2 & 1][c * 4096 + t * 8]);
  };
  auto stB = [&](int kt2, int c) {
    gld_lds16(pB + (size_t)kt2 * 64 + (size_t)c * 64 * K, &Bs[kt2 & 1][c * 4096 + t * 8]);
  };

  f32x4 acc[8][4] = {};
  bf16x8 a[4][2], b0[2][2], b1[2][2];

  // prologue: A(0) c0-c3, B(0) c0-c3, A(1) c0,c2; wait A0+B0 (leave 2)
  stA(0, 0); stA(0, 1); stA(0, 2); stA(0, 3);
  stB(0, 0); stB(0, 1); stB(0, 2); stB(0, 3);
  if (nt > 1) { stA(1, 0); stA(1, 2); }
  if (nt > 1) { asm volatile("s_waitcnt vmcnt(2)" ::: "memory"); }
  else        { asm volatile("s_waitcnt vmcnt(0)" ::: "memory"); }
  __builtin_amdgcn_s_barrier();

  for (int kt = 0; kt < nt; ++kt) {
    const unsigned short* as = As[kt & 1];
    const unsigned short* bs = Bs[kt & 1];
    bool p1 = kt + 1 < nt, p2 = kt + 2 < nt;

    // ---- q1 (mh0, nh0): read a0(8) + b0(4); stage B(T+1)c0,c1 ----
#pragma unroll
    for (int i = 0; i < 4; ++i) {
      a[i][0] = *(const bf16x8*)&as[(rA0 + i * 16) * 64 + ko0];
      a[i][1] = *(const bf16x8*)&as[(rA0 + i * 16) * 64 + ko1];
    }
#pragma unroll
    for (int ni = 0; ni < 2; ++ni) {
      b0[ni][0] = *(const bf16x8*)&bs[(rB0 + ni * 16) * 64 + ko0];
      b0[ni][1] = *(const bf16x8*)&bs[(rB0 + ni * 16) * 64 + ko1];
    }
    if (p1) { stB(kt + 1, 0); stB(kt + 1, 1); }
    PHASE_SYNC();
#pragma unroll
    for (int i = 0; i < 4; ++i)
#pragma unroll
      for (int ni = 0; ni < 2; ++ni)
#pragma unroll
        for (int ks = 0; ks < 2; ++ks)
          acc[i][ni] = __builtin_amdgcn_mfma_f32_16x16x32_bf16(a[i][ks], b0[ni][ks], acc[i][ni], 0, 0, 0);
    PHASE_END();

    // ---- q2 (mh0, nh1): read b1(4); stage B(T+1)c2,c3; vmcnt(5) ----
#pragma unroll
    for (int ni = 0; ni < 2; ++ni) {
      b1[ni][0] = *(const bf16x8*)&bs[(rB0 + 32 + ni * 16) * 64 + ko0];
      b1[ni][1] = *(const bf16x8*)&bs[(rB0 + 32 + ni * 16) * 64 + ko1];
    }
    if (p1) {
      stB(kt + 1, 2); stB(kt + 1, 3);
      asm volatile("s_waitcnt vmcnt(5)" ::: "memory");  // a1(T) landed
    } else {
      asm volatile("s_waitcnt vmcnt(0)" ::: "memory");
    }
    PHASE_SYNC();
#pragma unroll
    for (int i = 0; i < 4; ++i)
#pragma unroll
      for (int ni = 0; ni < 2; ++ni)
#pragma unroll
        for (int ks = 0; ks < 2; ++ks)
          acc[i][2 + ni] = __builtin_amdgcn_mfma_f32_16x16x32_bf16(a[i][ks], b1[ni][ks], acc[i][2 + ni], 0, 0, 0);
    PHASE_END();

    // ---- q3 (mh1, nh1): read a1(8); stage A(T+1)c1, A(T+2)c0 ----
#pragma unroll
    for (int i = 0; i < 4; ++i) {
      a[i][0] = *(const bf16x8*)&as[(rA0 + 64 + i * 16) * 64 + ko0];
      a[i][1] = *(const bf16x8*)&as[(rA0 + 64 + i * 16) * 64 + ko1];
    }
    if (p1) stA(kt + 1, 1);
    if (p2) stA(kt + 2, 0);
    PHASE_SYNC();
#pragma unroll
    for (int i = 0; i < 4; ++i)
#pragma unroll
      for (int ni = 0; ni < 2; ++ni)
#pragma unroll
        for (int ks = 0; ks < 2; ++ks)
          acc[4 + i][2 + ni] = __builtin_amdgcn_mfma_f32_16x16x32_bf16(a[i][ks], b1[ni][ks], acc[4 + i][2 + ni], 0, 0, 0);
    PHASE_END();

    // ---- q4 (mh1, nh0): no reads; stage A(T+1)c3, A(T+2)c2; vmcnt(4) ----
    if (p1) stA(kt + 1, 3);
    if (p2) stA(kt + 2, 2);
    if (p2)      { asm volatile("s_waitcnt vmcnt(4)" ::: "memory"); }  // tile T+1 ready
    else if (p1) { asm volatile("s_waitcnt vmcnt(2)" ::: "memory"); }  // tail: leave A(T+1)c1,c3? no: leave c3,? -> exact: [A(T+1)c1,A(T+1)c3] issued q3,q4 -> need none yet; but T+1 q1 needs A(T+1)c0,c2+B: all older -> drain to 2 keeps c1,c3 in flight
    else         { asm volatile("s_waitcnt vmcnt(0)" ::: "memory"); }
    PHASE_SYNC();
#pragma unroll
    for (int i = 0; i < 4; ++i)
#pragma unroll
      for (int ni = 0; ni < 2; ++ni)
#pragma unroll
        for (int ks = 0; ks < 2; ++ks)
          acc[4 + i][ni] = __builtin_amdgcn_mfma_f32_16x16x32_bf16(a[i][ks], b0[ni][ks], acc[4 + i][ni], 0, 0, 0);
    PHASE_END();
  }
  asm volatile("s_waitcnt vmcnt(0)" ::: "memory");

  // epilogue (16x16 C layout: col=lane&15, row=(lane>>4)*4+reg)
#pragma unroll
  for (int m = 0; m < 8; ++m) {
#pragma unroll
    for (int n = 0; n < 4; ++n) {
#pragma unroll
      for (int r = 0; r < 4; ++r) {
        int row = bm0 + wr * 128 + m * 16 + cl * 4 + r;
        int col = bn0 + wc * 64 + n * 16 + frr;
        size_t o = (size_t)row * N + col;
        float v = acc[m][n][r] + bias[col];
        if (SILU) v = v / (1.0f + __expf(-v));
        if (GATE) v = bf2f(gate[o]) * v + xres[o];
        if (RES) v += res[o];
        if (OUT_BF16)
          ((unsigned short*)Cv)[o] = f2bf(v);
        else
          ((float*)Cv)[o] = v;
      }
    }
  }
}

// ---------------------------------------------------------------------------
extern "C" void kernel_launch(void* const* d_in, const int* in_sizes, int n_in,
                              void* d_out, int out_size, void* d_ws, size_t ws_size,
                              hipStream_t stream) {
  const float* x      = (const float*)d_in[0];
  const float* ln_g   = (const float*)d_in[1];
  const float* ln_b   = (const float*)d_in[2];
  const float* fc_w   = (const float*)d_in[3];
  const float* fc_b   = (const float*)d_in[4];
  const float* w1     = (const float*)d_in[5];
  const float* b1     = (const float*)d_in[6];
  const float* w2     = (const float*)d_in[7];
  const float* b2     = (const float*)d_in[8];
  const float* ph_re  = (const float*)d_in[9];
  const float* ph_im  = (const float*)d_in[10];
  const float* phi_re = (const float*)d_in[11];
  const float* phi_im = (const float*)d_in[12];
  const float* lci_re = (const float*)d_in[13];
  const float* lci_im = (const float*)d_in[14];
  float* out = (float*)d_out;

  char* ws = (char*)d_ws;
  const size_t SZ_BF = (size_t)ROWS * D_ * 2;  // 33,554,432 bytes
  unsigned short* xn    = (unsigned short*)(ws);               // LN1 out (conv input)
  unsigned short* cbuf  = (unsigned short*)(ws + SZ_BF);       // conv output
  unsigned short* xb_x3 = (unsigned short*)(ws + 2 * SZ_BF);   // x bf16, then x3 (after gemm1)
  unsigned short* h1    = (unsigned short*)(ws + 3 * SZ_BF);   // [ROWS, FF] bf16 (2*SZ_BF)
  unsigned short* fc_wt = (unsigned short*)(ws + 5 * SZ_BF);
  unsigned short* w1t   = (unsigned short*)(ws + 5 * SZ_BF + (size_t)D_ * D_ * 2);
  unsigned short* w2t   = (unsigned short*)(ws + 5 * SZ_BF + (size_t)D_ * D_ * 2 + (size_t)D_ * FF_ * 2);
  float2* rloc  = (float2*)(ws + 5 * SZ_BF + (size_t)D_ * D_ * 2 + 2 * (size_t)D_ * FF_ * 2);
  float2* carry = rloc + (size_t)B_ * CG * D_;

  // weight prep (bf16, transposed to [N,K])
  transpose_cast<<<dim3(D_ / 32, D_ / 32), 256, 0, stream>>>(fc_w, fc_wt, D_, D_);
  transpose_cast<<<dim3(FF_ / 32, D_ / 32), 256, 0, stream>>>(w1, w1t, D_, FF_);
  transpose_cast<<<dim3(D_ / 32, FF_ / 32), 256, 0, stream>>>(w2, w2t, FF_, D_);

  // LN1 + cast
  ln1_kernel<<<ROWS, 256, 0, stream>>>(x, ln_g, ln_b, xn, xb_x3);

  // conv (chunked scan)
  conv_pass1<<<dim3(D_ / 256, CG, B_), 256, 0, stream>>>(xn, ph_re, ph_im, rloc);
  conv_pass2<<<dim3((B_ * D_) / 256), 256, 0, stream>>>(ph_re, ph_im, rloc, carry);
  conv_pass3<<<dim3(D_ / 256, CG, B_), 256, 0, stream>>>(xn, ph_re, ph_im, phi_re, phi_im,
                                                         lci_re, lci_im, carry, cbuf);

  // x2 = c * silu(x @ fc_w + fc_b) + x  (fused gate, f32 -> d_out)
  gemm_bt<1, 0, 0, 1><<<(ROWS / 256) * (D_ / 256), 512, 0, stream>>>(
      xb_x3, fc_wt, fc_b, nullptr, cbuf, x, out, D_ / 256, 4, D_, D_);

  // x3 = LN(x2) (bf16, reuses xb region)
  ln2b_kernel<<<ROWS, 256, 0, stream>>>(out, ln_g, ln_b, xb_x3);

  // h1 = silu(x3 @ w1 + b1)
  gemm_bt<1, 0, 1, 0><<<(ROWS / 256) * (FF_ / 256), 512, 0, stream>>>(
      xb_x3, w1t, b1, nullptr, nullptr, nullptr, h1, FF_ / 256, 4, FF_, D_);

  // out = x2 + h1 @ w2 + b2   (in-place residual from d_out)
  gemm_bt<0, 1, 0, 0><<<(ROWS / 256) * (D_ / 256), 512, 0, stream>>>(
      h1, w2t, b2, out, nullptr, nullptr, out, D_ / 256, 2, D_, FF_);
}